// Round 2
// baseline (261.275 us; speedup 1.0000x reference)
//
#include <hip/hip_runtime.h>
#include <hip/hip_bf16.h>
#include <math.h>

// NoisyTopkRouter round 8: barrier-free main loop.
// Post-mortem r7: occupancy 19.5->33.6 with ZERO speedup -> not TLP-bound.
// Diagnosis: per-stage __syncthreads forces s_waitcnt vmcnt(0) drain (compiler
// emits full drain before s_barrier), collapsing all prefetch depth; every
// wave in every block stalls synchronously on global latency once per stage
// (~12.7k cyc/stage span vs ~1.5k cyc of issue work).
// Fix: drop LDS A-staging entirely. Each wave loads its A-fragments directly
// from global in MFMA frag order (lane(n16,quad) -> 32B contiguous; wave =
// 16 rows x 128B full lines, one 128B line per row per K=32 chunk). The 4x
// intra-block duplication of A reads is L1/L2-served (4KB/chunk working set).
// cvt8 now runs per-wave (4x VALU vs staged — VALU was only 19% busy).
// Main loop has NO barriers; register-only depth-2 pipeline on raw A.
// Numerics identical: bf16 hi/lo split, 3-term MFMA (hixhi, hixlo, loxhi).

#define T_TOKENS 32768
#define D_MODEL  1024
#define NE       64
#define NCOL     128
#define M_TILE   32
#define NCHUNK   32
#define CS_LD    68
#define OUT_IDX_BASE ((size_t)T_TOKENS * NE)
#define W_ELEMS  (NCOL * D_MODEL)

typedef short  bf16x8  __attribute__((ext_vector_type(8)));
typedef float  floatx4 __attribute__((ext_vector_type(4)));

__device__ __forceinline__ float softplus_f(float x) {
    return fmaxf(x, 0.f) + log1pf(expf(-fabsf(x)));
}

// 8 floats -> packed bf16 hi (int4) + bf16 lo (int4). RNE hi, exact residual,
// RNE lo — numerically identical to rounds 2-7.
__device__ __forceinline__ void cvt8(const float4 a, const float4 b,
                                     int4* hi, int4* lo) {
    float v[8] = {a.x, a.y, a.z, a.w, b.x, b.y, b.z, b.w};
    int hw[4], lw[4];
    #pragma unroll
    for (int p = 0; p < 4; ++p) {
        float2 f2 = make_float2(v[2 * p], v[2 * p + 1]);
        __hip_bfloat162 h2 = __float22bfloat162_rn(f2);
        int u; __builtin_memcpy(&u, &h2, 4);
        float h0 = __uint_as_float(((unsigned)u) << 16);
        float h1 = __uint_as_float(((unsigned)u) & 0xFFFF0000u);
        float2 l2 = make_float2(v[2 * p] - h0, v[2 * p + 1] - h1);
        __hip_bfloat162 L2 = __float22bfloat162_rn(l2);
        int ul; __builtin_memcpy(&ul, &L2, 4);
        hw[p] = u; lw[p] = ul;
    }
    *hi = make_int4(hw[0], hw[1], hw[2], hw[3]);
    *lo = make_int4(lw[0], lw[1], lw[2], lw[3]);
}

__device__ __forceinline__ void cvt8r(const float4 a, const float4 b,
                                      bf16x8* hi, bf16x8* lo) {
    int4 h, l;
    cvt8(a, b, &h, &l);
    __builtin_memcpy(hi, &h, 16);
    __builtin_memcpy(lo, &l, 16);
}

// ---------------- prepack: W -> hi/lo bf16 in B-frag order ----------------
// elem index = ((ntile*128 + kgrp)*16 + n16)*8 + j ; value = W[ntile*16+n16][kgrp*8+j]
__global__ __launch_bounds__(256) void prepack_w(
    const float* __restrict__ Wr, const float* __restrict__ Wn,
    short* __restrict__ Bh, short* __restrict__ Bl)
{
    int g   = blockIdx.x * 256 + threadIdx.x;
    int n   = g & 15;
    int kg  = (g >> 4) & 127;
    int t2  = g >> 11;
    int col = t2 * 16 + n;
    const float* src = (col < NE ? Wr + (size_t)col * D_MODEL
                                 : Wn + (size_t)(col - NE) * D_MODEL) + kg * 8;
    float4 a = *(const float4*)src;
    float4 b = *(const float4*)(src + 4);
    int4 hi, lo;
    cvt8(a, b, &hi, &lo);
    *(int4*)(Bh + (size_t)g * 8) = hi;
    *(int4*)(Bl + (size_t)g * 8) = lo;
}

// ---------------- main fused kernel ----------------
__global__ __launch_bounds__(256, 4) void router_mfma(
    const float* __restrict__ A,
    const float* __restrict__ noise,
    const float* __restrict__ br,
    const float* __restrict__ bn,
    const short* __restrict__ Bh,
    const short* __restrict__ Bl,
    float* __restrict__ out)
{
    __shared__ float Cs[M_TILE * CS_LD];
    __shared__ float s_p1[M_TILE], s_p2[M_TILE];
    __shared__ int   s_e1[M_TILE], s_e2[M_TILE];

    const int tid  = threadIdx.x;
    const int lane = tid & 63;
    const int wid  = tid >> 6;   // wave: route ntile wid, noise ntile wid+4
    const int n16  = lane & 15;
    const int quad = lane >> 4;
    const int m0   = blockIdx.x * M_TILE;

    // Direct A-fragment pointers: lane holds A[row = mf*16+n16][k = kc*32+quad*8+j]
    const float* pA0 = A + (size_t)(m0 + n16) * D_MODEL + quad * 8;       // mf=0
    const float* pA1 = pA0 + (size_t)16 * D_MODEL;                        // mf=1

    const short* pBhR = Bh + ((size_t)(wid * 128 + quad) * 16 + n16) * 8;
    const short* pBlR = Bl + ((size_t)(wid * 128 + quad) * 16 + n16) * 8;
    const short* pBhN = Bh + ((size_t)((4 + wid) * 128 + quad) * 16 + n16) * 8;
    const short* pBlN = Bl + ((size_t)((4 + wid) * 128 + quad) * 16 + n16) * 8;

    floatx4 acc[2][2];   // [m-frag][route/noise]
    #pragma unroll
    for (int i = 0; i < 2; ++i) { acc[i][0] = (floatx4)0.f; acc[i][1] = (floatx4)0.f; }

    // ---- register pipeline: raw A for chunks kc (c*) and kc+1 (n*) ----
    float4 c0a = *(const float4*)(pA0);
    float4 c0b = *(const float4*)(pA0 + 4);
    float4 c1a = *(const float4*)(pA1);
    float4 c1b = *(const float4*)(pA1 + 4);
    float4 n0a = *(const float4*)(pA0 + 32);
    float4 n0b = *(const float4*)(pA0 + 36);
    float4 n1a = *(const float4*)(pA1 + 32);
    float4 n1b = *(const float4*)(pA1 + 36);

    for (int kc = 0; kc < NCHUNK; ++kc) {
        // issue raw A for chunk kc+2 (depth-2; no barrier ever drains these)
        float4 t0a, t0b, t1a, t1b;
        if (kc + 2 < NCHUNK) {
            const float* q0 = pA0 + (kc + 2) * 32;
            const float* q1 = pA1 + (kc + 2) * 32;
            t0a = *(const float4*)(q0);
            t0b = *(const float4*)(q0 + 4);
            t1a = *(const float4*)(q1);
            t1b = *(const float4*)(q1 + 4);
        }

        // B frags for this chunk (L2-resident, 512B stride per chunk)
        const int o = kc * 512;
        bf16x8 bhR = *(const bf16x8*)(pBhR + o);
        bf16x8 blR = *(const bf16x8*)(pBlR + o);
        bf16x8 bhN = *(const bf16x8*)(pBhN + o);
        bf16x8 blN = *(const bf16x8*)(pBlN + o);

        // convert current chunk's A to hi/lo bf16 frags (in-register)
        bf16x8 ah0, al0, ah1, al1;
        cvt8r(c0a, c0b, &ah0, &al0);
        cvt8r(c1a, c1b, &ah1, &al1);

        // 12 MFMAs (4 independent acc chains, 3-term products)
        acc[0][0] = __builtin_amdgcn_mfma_f32_16x16x32_bf16(ah0, bhR, acc[0][0], 0, 0, 0);
        acc[0][0] = __builtin_amdgcn_mfma_f32_16x16x32_bf16(ah0, blR, acc[0][0], 0, 0, 0);
        acc[0][0] = __builtin_amdgcn_mfma_f32_16x16x32_bf16(al0, bhR, acc[0][0], 0, 0, 0);
        acc[0][1] = __builtin_amdgcn_mfma_f32_16x16x32_bf16(ah0, bhN, acc[0][1], 0, 0, 0);
        acc[0][1] = __builtin_amdgcn_mfma_f32_16x16x32_bf16(ah0, blN, acc[0][1], 0, 0, 0);
        acc[0][1] = __builtin_amdgcn_mfma_f32_16x16x32_bf16(al0, bhN, acc[0][1], 0, 0, 0);
        acc[1][0] = __builtin_amdgcn_mfma_f32_16x16x32_bf16(ah1, bhR, acc[1][0], 0, 0, 0);
        acc[1][0] = __builtin_amdgcn_mfma_f32_16x16x32_bf16(ah1, blR, acc[1][0], 0, 0, 0);
        acc[1][0] = __builtin_amdgcn_mfma_f32_16x16x32_bf16(al1, bhR, acc[1][0], 0, 0, 0);
        acc[1][1] = __builtin_amdgcn_mfma_f32_16x16x32_bf16(ah1, bhN, acc[1][1], 0, 0, 0);
        acc[1][1] = __builtin_amdgcn_mfma_f32_16x16x32_bf16(ah1, blN, acc[1][1], 0, 0, 0);
        acc[1][1] = __builtin_amdgcn_mfma_f32_16x16x32_bf16(al1, bhN, acc[1][1], 0, 0, 0);

        // shift pipeline
        c0a = n0a; c0b = n0b; c1a = n1a; c1b = n1b;
        n0a = t0a; n0b = t0b; n1a = t1a; n1b = t1b;
    }

    // ---- lane-local fuse: noisy = route + noise * softplus(noise_logit) ----
    // D layout: col = lane&15 (expert within ntile), row = quad*4 + rr
    {
        int e = wid * 16 + n16;
        float brv = br[e], bnv = bn[e];
        #pragma unroll
        for (int mf = 0; mf < 2; ++mf)
            #pragma unroll
            for (int rr = 0; rr < 4; ++rr) {
                int t = mf * 16 + quad * 4 + rr;
                float nz    = noise[(size_t)(m0 + t) * NE + e];
                float route = acc[mf][0][rr] + brv;
                float nl    = acc[mf][1][rr] + bnv;
                Cs[t * CS_LD + e] = fmaf(nz, softplus_f(nl), route);
            }
    }
    __syncthreads();

    // ---- top-2 + softmax (one thread per token; in-order scan = stable ties) ----
    if (tid < M_TILE) {
        const int t = tid;
        float v1 = -INFINITY, v2 = -INFINITY;
        int e1 = 0, e2 = 0;
        #pragma unroll
        for (int e4 = 0; e4 < 16; ++e4) {
            float4 q = *(const float4*)&Cs[t * CS_LD + e4 * 4];
            float qa[4] = {q.x, q.y, q.z, q.w};
            #pragma unroll
            for (int c = 0; c < 4; ++c) {
                float v = qa[c];
                int e = e4 * 4 + c;
                if (v > v1) { v2 = v1; e2 = e1; v1 = v; e1 = e; }
                else if (v > v2) { v2 = v; e2 = e; }
            }
        }
        float ex = expf(v2 - v1);
        float denom = 1.f + ex;
        s_p1[t] = 1.f / denom;
        s_p2[t] = ex / denom;
        s_e1[t] = e1;
        s_e2[t] = e2;
        float2 iv = make_float2((float)e1, (float)e2);
        *(float2*)(out + OUT_IDX_BASE + (size_t)(m0 + t) * 2) = iv;
    }
    __syncthreads();

    // ---- coalesced scatter of router_output [32 tokens x 64 experts] ----
    #pragma unroll
    for (int i = 0; i < 2; ++i) {
        int gi = i * 256 + tid;       // 0..511 float4s
        int t  = gi >> 4;
        int e0 = (gi & 15) * 4;
        float p1 = s_p1[t], p2 = s_p2[t];
        int   e1 = s_e1[t], e2 = s_e2[t];
        float4 v;
        v.x = (e0 + 0 == e1) ? p1 : ((e0 + 0 == e2) ? p2 : 0.f);
        v.y = (e0 + 1 == e1) ? p1 : ((e0 + 1 == e2) ? p2 : 0.f);
        v.z = (e0 + 2 == e1) ? p1 : ((e0 + 2 == e2) ? p2 : 0.f);
        v.w = (e0 + 3 == e1) ? p1 : ((e0 + 3 == e2) ? p2 : 0.f);
        *(float4*)(out + (size_t)(m0 + t) * NE + e0) = v;
    }
}

extern "C" void kernel_launch(void* const* d_in, const int* in_sizes, int n_in,
                              void* d_out, int out_size, void* d_ws, size_t ws_size,
                              hipStream_t stream) {
    const float* A     = (const float*)d_in[0];
    const float* noise = (const float*)d_in[1];
    const float* Wr    = (const float*)d_in[2];
    const float* br    = (const float*)d_in[3];
    const float* Wn    = (const float*)d_in[4];
    const float* bn    = (const float*)d_in[5];
    float* out = (float*)d_out;

    short* Bh = (short*)d_ws;
    short* Bl = Bh + W_ELEMS;

    prepack_w<<<dim3(W_ELEMS / 8 / 256), dim3(256), 0, stream>>>(Wr, Wn, Bh, Bl);
    router_mfma<<<dim3(T_TOKENS / M_TILE), dim3(256), 0, stream>>>(A, noise, br, bn, Bh, Bl, out);
}

// Round 3
// 236.785 us; speedup vs baseline: 1.1034x; 1.1034x over previous
//
#include <hip/hip_runtime.h>
#include <hip/hip_bf16.h>
#include <math.h>

// NoisyTopkRouter round 9: LDS-DMA deep pipeline (T3+T4 adaptation).
// Post-mortems r7/r8: occupancy x2 -> no change; barrier-free -> worse;
// r8 L3-resident dispatches (8.6MB fetch) ran SAME 113us as cold (73MB)
// -> pure latency-bound. Little's law: VGPR-held prefetch gives only
// ~1-2.5KB in flight per CU vs ~9.2KB needed -> ~1TB/s cap == measured.
// Fix: global_load_lds ring (depth 4 x 8KB fp32 chunks), raw s_barrier
// (no compiler vmcnt(0) drain) + hand-counted vmcnt(4) so chunks c+1..c+3
// stay in flight across barriers (16-24KB/block in flight).
// - vmcnt(4) is B-load-placement-independent: DMA(c) always has >=4
//   younger DMA instrs (DMA(c+1),DMA(c+2)) at the wait point.
// - LDS chunk = row-major [64][128B] fp32 with XOR swizzle
//   byte ^= ((row&7)<<4), applied on DMA *source* address (dest must be
//   lane-linear) and on ds_read addresses. G4-proven conflict fix.
// - cvt8 per-wave (x4 dup; VALU was only 21% busy).
// Numerics identical: bf16 hi/lo split, 3-term MFMA, same epilogue.

#define T_TOKENS 32768
#define D_MODEL  1024
#define NE       64
#define NCOL     128
#define M_TILE   64
#define NCHUNK   32
#define RING_D   4
#define CS_LD    68
#define OUT_IDX_BASE ((size_t)T_TOKENS * NE)
#define W_ELEMS  (NCOL * D_MODEL)

typedef short  bf16x8  __attribute__((ext_vector_type(8)));
typedef float  floatx4 __attribute__((ext_vector_type(4)));
typedef const __attribute__((address_space(1))) unsigned int gu32;
typedef __attribute__((address_space(3))) unsigned int lu32;

__device__ __forceinline__ float softplus_f(float x) {
    return fmaxf(x, 0.f) + log1pf(expf(-fabsf(x)));
}

// 8 floats -> packed bf16 hi (int4) + bf16 lo (int4). RNE hi, exact residual,
// RNE lo — numerically identical to rounds 2-8.
__device__ __forceinline__ void cvt8(const float4 a, const float4 b,
                                     int4* hi, int4* lo) {
    float v[8] = {a.x, a.y, a.z, a.w, b.x, b.y, b.z, b.w};
    int hw[4], lw[4];
    #pragma unroll
    for (int p = 0; p < 4; ++p) {
        float2 f2 = make_float2(v[2 * p], v[2 * p + 1]);
        __hip_bfloat162 h2 = __float22bfloat162_rn(f2);
        int u; __builtin_memcpy(&u, &h2, 4);
        float h0 = __uint_as_float(((unsigned)u) << 16);
        float h1 = __uint_as_float(((unsigned)u) & 0xFFFF0000u);
        float2 l2 = make_float2(v[2 * p] - h0, v[2 * p + 1] - h1);
        __hip_bfloat162 L2 = __float22bfloat162_rn(l2);
        int ul; __builtin_memcpy(&ul, &L2, 4);
        hw[p] = u; lw[p] = ul;
    }
    *hi = make_int4(hw[0], hw[1], hw[2], hw[3]);
    *lo = make_int4(lw[0], lw[1], lw[2], lw[3]);
}

__device__ __forceinline__ void cvt8r(const float4 a, const float4 b,
                                      bf16x8* hi, bf16x8* lo) {
    int4 h, l;
    cvt8(a, b, &h, &l);
    __builtin_memcpy(hi, &h, 16);
    __builtin_memcpy(lo, &l, 16);
}

// ---------------- prepack: W -> hi/lo bf16 in B-frag order ----------------
// elem index = ((ntile*128 + kgrp)*16 + n16)*8 + j ; value = W[ntile*16+n16][kgrp*8+j]
__global__ __launch_bounds__(256) void prepack_w(
    const float* __restrict__ Wr, const float* __restrict__ Wn,
    short* __restrict__ Bh, short* __restrict__ Bl)
{
    int g   = blockIdx.x * 256 + threadIdx.x;
    int n   = g & 15;
    int kg  = (g >> 4) & 127;
    int t2  = g >> 11;
    int col = t2 * 16 + n;
    const float* src = (col < NE ? Wr + (size_t)col * D_MODEL
                                 : Wn + (size_t)(col - NE) * D_MODEL) + kg * 8;
    float4 a = *(const float4*)src;
    float4 b = *(const float4*)(src + 4);
    int4 hi, lo;
    cvt8(a, b, &hi, &lo);
    *(int4*)(Bh + (size_t)g * 8) = hi;
    *(int4*)(Bl + (size_t)g * 8) = lo;
}

// ---------------- main fused kernel ----------------
__global__ __launch_bounds__(256, 2) void router_mfma(
    const float* __restrict__ A,
    const float* __restrict__ noise,
    const float* __restrict__ br,
    const float* __restrict__ bn,
    const short* __restrict__ Bh,
    const short* __restrict__ Bl,
    float* __restrict__ out)
{
    // fp32 A ring: RING_D chunks x 64 rows x 32 floats (128B/row), swizzled.
    __shared__ __align__(16) float ringA[RING_D * M_TILE * 32];
    __shared__ float Cs[M_TILE * CS_LD];
    __shared__ float s_p1[M_TILE], s_p2[M_TILE];
    __shared__ int   s_e1[M_TILE], s_e2[M_TILE];

    const int tid  = threadIdx.x;
    const int lane = tid & 63;
    const int wid  = tid >> 6;   // wave: route ntile wid, noise ntile wid+4
    const int n16  = lane & 15;
    const int quad = lane >> 4;
    const int m0   = blockIdx.x * M_TILE;

    // ---- DMA source addressing (pre-swizzled so linear LDS == swizzled) ----
    // instr j (j = 2*wid, 2*wid+1): lane l stages 16B of row j*8 + (l>>3),
    // col floats kc*32 + ((l&7)^(l>>3))*4. Each instr = 8 full 128B lines.
    const int rlo = lane >> 3;                     // 0..7
    const int csw = ((lane & 7) ^ rlo) * 4;        // swizzled float offset
    const int j0  = 2 * wid;
    const float* srcA0 = A + (size_t)(m0 + j0 * 8 + rlo) * D_MODEL + csw;
    const float* srcA1 = A + (size_t)(m0 + j0 * 8 + 8 + rlo) * D_MODEL + csw;

    // ds_read swizzled float offsets (row term added separately):
    // byte = row*128 + ((quad*32 + h*16) ^ ((row&7)<<4)); row&7 == n16&7.
    const int sw0 = (((quad * 32 +  0) ^ ((n16 & 7) << 4)) >> 2);
    const int sw1 = (((quad * 32 + 16) ^ ((n16 & 7) << 4)) >> 2);

    const short* pBhR = Bh + ((size_t)(wid * 128 + quad) * 16 + n16) * 8;
    const short* pBlR = Bl + ((size_t)(wid * 128 + quad) * 16 + n16) * 8;
    const short* pBhN = Bh + ((size_t)((4 + wid) * 128 + quad) * 16 + n16) * 8;
    const short* pBlN = Bl + ((size_t)((4 + wid) * 128 + quad) * 16 + n16) * 8;

#define DMA_CHUNK(KC_) do {                                                   \
        const int b_ = (KC_) & (RING_D - 1);                                  \
        __builtin_amdgcn_global_load_lds(                                     \
            (gu32*)(srcA0 + (KC_) * 32),                                      \
            (lu32*)(ringA + b_ * (M_TILE * 32) + j0 * 256), 16, 0, 0);        \
        __builtin_amdgcn_global_load_lds(                                     \
            (gu32*)(srcA1 + (KC_) * 32),                                      \
            (lu32*)(ringA + b_ * (M_TILE * 32) + (j0 + 1) * 256), 16, 0, 0);  \
    } while (0)

    floatx4 acc[4][2];   // [m-frag][route/noise]
    #pragma unroll
    for (int i = 0; i < 4; ++i) { acc[i][0] = (floatx4)0.f; acc[i][1] = (floatx4)0.f; }

    // ---- prologue: DMA chunks 0..2; B(0) into regs ----
    DMA_CHUNK(0);
    DMA_CHUNK(1);
    DMA_CHUNK(2);
    bf16x8 bhR = *(const bf16x8*)(pBhR);
    bf16x8 blR = *(const bf16x8*)(pBlR);
    bf16x8 bhN = *(const bf16x8*)(pBhN);
    bf16x8 blN = *(const bf16x8*)(pBlN);

    for (int kc = 0; kc < NCHUNK; ++kc) {
        const int buf = kc & (RING_D - 1);

        __builtin_amdgcn_sched_barrier(0);
        // counted wait: DMA(kc) has exactly {DMA(kc+1), DMA(kc+2)} younger
        // DMA instrs here (4 wave-instrs) -> vmcnt(4) guarantees it landed,
        // independent of where the compiler placed B loads. Tail shrinks.
        if (kc < NCHUNK - 2)       asm volatile("s_waitcnt vmcnt(4)" ::: "memory");
        else if (kc == NCHUNK - 2) asm volatile("s_waitcnt vmcnt(2)" ::: "memory");
        else                       asm volatile("s_waitcnt vmcnt(0)" ::: "memory");
        __builtin_amdgcn_s_barrier();      // raw barrier: no compiler drain
        __builtin_amdgcn_sched_barrier(0);

        // issue DMA for chunk kc+3 (writes slot (kc-1)&3 — all waves are past
        // barrier(kc), so their chunk kc-1 reads were consumed last iter).
        if (kc + RING_D - 1 < NCHUNK) DMA_CHUNK(kc + RING_D - 1);

        // B regs for next chunk (clamped on last iter; value unused then)
        const int on = (kc + 1 < NCHUNK ? kc + 1 : kc) * 512;
        bf16x8 nbhR = *(const bf16x8*)(pBhR + on);
        bf16x8 nblR = *(const bf16x8*)(pBlR + on);
        bf16x8 nbhN = *(const bf16x8*)(pBhN + on);
        bf16x8 nblN = *(const bf16x8*)(pBlN + on);

        // frag reads: fp32, 2x ds_read_b128 per mf, XOR-swizzled (2-way max)
        float4 fa[4], fb[4];
        #pragma unroll
        for (int mf = 0; mf < 4; ++mf) {
            const float* p = &ringA[buf * (M_TILE * 32) + (mf * 16 + n16) * 32];
            fa[mf] = *(const float4*)(p + sw0);
            fb[mf] = *(const float4*)(p + sw1);
        }

        // cvt + 24 MFMAs (8 independent acc chains, depth 3)
        #pragma unroll
        for (int mf = 0; mf < 4; ++mf) {
            bf16x8 ah, al;
            cvt8r(fa[mf], fb[mf], &ah, &al);
            acc[mf][0] = __builtin_amdgcn_mfma_f32_16x16x32_bf16(ah, bhR, acc[mf][0], 0, 0, 0);
            acc[mf][0] = __builtin_amdgcn_mfma_f32_16x16x32_bf16(ah, blR, acc[mf][0], 0, 0, 0);
            acc[mf][0] = __builtin_amdgcn_mfma_f32_16x16x32_bf16(al, bhR, acc[mf][0], 0, 0, 0);
            acc[mf][1] = __builtin_amdgcn_mfma_f32_16x16x32_bf16(ah, bhN, acc[mf][1], 0, 0, 0);
            acc[mf][1] = __builtin_amdgcn_mfma_f32_16x16x32_bf16(ah, blN, acc[mf][1], 0, 0, 0);
            acc[mf][1] = __builtin_amdgcn_mfma_f32_16x16x32_bf16(al, bhN, acc[mf][1], 0, 0, 0);
        }

        bhR = nbhR; blR = nblR; bhN = nbhN; blN = nblN;
    }
#undef DMA_CHUNK

    // ---- lane-local fuse: noisy = route + noise * softplus(noise_logit) ----
    // D layout: col = lane&15 (expert within ntile), row = quad*4 + rr
    {
        int e = wid * 16 + n16;
        float brv = br[e], bnv = bn[e];
        #pragma unroll
        for (int mf = 0; mf < 4; ++mf)
            #pragma unroll
            for (int rr = 0; rr < 4; ++rr) {
                int t = mf * 16 + quad * 4 + rr;
                float nz    = noise[(size_t)(m0 + t) * NE + e];
                float route = acc[mf][0][rr] + brv;
                float nl    = acc[mf][1][rr] + bnv;
                Cs[t * CS_LD + e] = fmaf(nz, softplus_f(nl), route);
            }
    }
    __syncthreads();

    // ---- top-2 + softmax (one thread per token; in-order scan = stable ties) ----
    if (tid < M_TILE) {
        const int t = tid;
        float v1 = -INFINITY, v2 = -INFINITY;
        int e1 = 0, e2 = 0;
        #pragma unroll
        for (int e4 = 0; e4 < 16; ++e4) {
            float4 q = *(const float4*)&Cs[t * CS_LD + e4 * 4];
            float qa[4] = {q.x, q.y, q.z, q.w};
            #pragma unroll
            for (int c = 0; c < 4; ++c) {
                float v = qa[c];
                int e = e4 * 4 + c;
                if (v > v1) { v2 = v1; e2 = e1; v1 = v; e1 = e; }
                else if (v > v2) { v2 = v; e2 = e; }
            }
        }
        float ex = expf(v2 - v1);
        float denom = 1.f + ex;
        s_p1[t] = 1.f / denom;
        s_p2[t] = ex / denom;
        s_e1[t] = e1;
        s_e2[t] = e2;
        float2 iv = make_float2((float)e1, (float)e2);
        *(float2*)(out + OUT_IDX_BASE + (size_t)(m0 + t) * 2) = iv;
    }
    __syncthreads();

    // ---- coalesced scatter of router_output [64 tokens x 64 experts] ----
    #pragma unroll
    for (int i = 0; i < 4; ++i) {
        int gi = i * 256 + tid;       // 0..1023 float4s
        int t  = gi >> 4;
        int e0 = (gi & 15) * 4;
        float p1 = s_p1[t], p2 = s_p2[t];
        int   e1 = s_e1[t], e2 = s_e2[t];
        float4 v;
        v.x = (e0 + 0 == e1) ? p1 : ((e0 + 0 == e2) ? p2 : 0.f);
        v.y = (e0 + 1 == e1) ? p1 : ((e0 + 1 == e2) ? p2 : 0.f);
        v.z = (e0 + 2 == e1) ? p1 : ((e0 + 2 == e2) ? p2 : 0.f);
        v.w = (e0 + 3 == e1) ? p1 : ((e0 + 3 == e2) ? p2 : 0.f);
        *(float4*)(out + (size_t)(m0 + t) * NE + e0) = v;
    }
}

extern "C" void kernel_launch(void* const* d_in, const int* in_sizes, int n_in,
                              void* d_out, int out_size, void* d_ws, size_t ws_size,
                              hipStream_t stream) {
    const float* A     = (const float*)d_in[0];
    const float* noise = (const float*)d_in[1];
    const float* Wr    = (const float*)d_in[2];
    const float* br    = (const float*)d_in[3];
    const float* Wn    = (const float*)d_in[4];
    const float* bn    = (const float*)d_in[5];
    float* out = (float*)d_out;

    short* Bh = (short*)d_ws;
    short* Bl = Bh + W_ELEMS;

    prepack_w<<<dim3(W_ELEMS / 8 / 256), dim3(256), 0, stream>>>(Wr, Wn, Bh, Bl);
    router_mfma<<<dim3(T_TOKENS / M_TILE), dim3(256), 0, stream>>>(A, noise, br, bn, Bh, Bl, out);
}

// Round 4
// 234.329 us; speedup vs baseline: 1.1150x; 1.0105x over previous
//
#include <hip/hip_runtime.h>
#include <hip/hip_bf16.h>
#include <math.h>

// NoisyTopkRouter round 10: exact-counted dual-stream pipeline.
// Post-mortem r9: vmcnt counts ALL VMEM per wave -> per-wave B-reg loads
// polluted the counted waits; compiler's own B-use wait drained DMA(kc+1)
// every iter -> prefetch depth ~1. All 4 structures so far (r6-r9) end up
// MLP-starved (~1 TB/s, all utils <33%, waves ~85% in memory waits).
// Fix: pin per-wave VMEM issue order with sched_barrier(0) fences and derive
// exact vmcnt values from the fully-determined queue:
//   iter kc: [issue B(kc+2):4] SB [s_waitcnt vmcnt(N)] [s_barrier] SB
//            [issue A-DMA(kc+3):2] [ds_read slot kc, cvt, 24 MFMA]
//   steady queue at wait (old->young): B(kc),A(kc+1),B(kc+1),A(kc+2),B(kc+2)=16
//   vmcnt(12) retires exactly B(kc) (A(kc) retired an iter earlier).
//   In flight after wait: A(kc+2),A(kc+3),B(kc+1),B(kc+2) ~ 20KB/block.
// DMA issued AFTER barrier: slot (kc+3)%4 == (kc-1)%4 and all waves' reads
// of chunk kc-1 retired before their MFMA(kc-1) (lgkm), which precede this
// barrier -> no ring race. B in named 3-stage reg rotation (no dyn index).
// A ring: raw fp32, linear layout both sides (rule 21). cvt8 per-wave.
// Numerics identical: bf16 hi/lo split, 3-term MFMA, same epilogue.

#define T_TOKENS 32768
#define D_MODEL  1024
#define NE       64
#define NCOL     128
#define M_TILE   64
#define NCHUNK   32
#define RING_D   4
#define CS_LD    68
#define OUT_IDX_BASE ((size_t)T_TOKENS * NE)
#define W_ELEMS  (NCOL * D_MODEL)

typedef short  bf16x8  __attribute__((ext_vector_type(8)));
typedef float  floatx4 __attribute__((ext_vector_type(4)));
typedef const __attribute__((address_space(1))) unsigned int gu32;
typedef __attribute__((address_space(3))) unsigned int lu32;

__device__ __forceinline__ float softplus_f(float x) {
    return fmaxf(x, 0.f) + log1pf(expf(-fabsf(x)));
}

// 8 floats -> packed bf16 hi (int4) + bf16 lo (int4). RNE hi, exact residual,
// RNE lo — numerically identical to rounds 2-9.
__device__ __forceinline__ void cvt8(const float4 a, const float4 b,
                                     int4* hi, int4* lo) {
    float v[8] = {a.x, a.y, a.z, a.w, b.x, b.y, b.z, b.w};
    int hw[4], lw[4];
    #pragma unroll
    for (int p = 0; p < 4; ++p) {
        float2 f2 = make_float2(v[2 * p], v[2 * p + 1]);
        __hip_bfloat162 h2 = __float22bfloat162_rn(f2);
        int u; __builtin_memcpy(&u, &h2, 4);
        float h0 = __uint_as_float(((unsigned)u) << 16);
        float h1 = __uint_as_float(((unsigned)u) & 0xFFFF0000u);
        float2 l2 = make_float2(v[2 * p] - h0, v[2 * p + 1] - h1);
        __hip_bfloat162 L2 = __float22bfloat162_rn(l2);
        int ul; __builtin_memcpy(&ul, &L2, 4);
        hw[p] = u; lw[p] = ul;
    }
    *hi = make_int4(hw[0], hw[1], hw[2], hw[3]);
    *lo = make_int4(lw[0], lw[1], lw[2], lw[3]);
}

__device__ __forceinline__ void cvt8r(const float4 a, const float4 b,
                                      bf16x8* hi, bf16x8* lo) {
    int4 h, l;
    cvt8(a, b, &h, &l);
    __builtin_memcpy(hi, &h, 16);
    __builtin_memcpy(lo, &l, 16);
}

// ---------------- prepack: W -> hi/lo bf16 in B-frag order ----------------
// elem index = ((ntile*128 + kgrp)*16 + n16)*8 + j ; value = W[ntile*16+n16][kgrp*8+j]
__global__ __launch_bounds__(256) void prepack_w(
    const float* __restrict__ Wr, const float* __restrict__ Wn,
    short* __restrict__ Bh, short* __restrict__ Bl)
{
    int g   = blockIdx.x * 256 + threadIdx.x;
    int n   = g & 15;
    int kg  = (g >> 4) & 127;
    int t2  = g >> 11;
    int col = t2 * 16 + n;
    const float* src = (col < NE ? Wr + (size_t)col * D_MODEL
                                 : Wn + (size_t)(col - NE) * D_MODEL) + kg * 8;
    float4 a = *(const float4*)src;
    float4 b = *(const float4*)(src + 4);
    int4 hi, lo;
    cvt8(a, b, &hi, &lo);
    *(int4*)(Bh + (size_t)g * 8) = hi;
    *(int4*)(Bl + (size_t)g * 8) = lo;
}

// ---------------- main fused kernel ----------------
__global__ __launch_bounds__(256, 2) void router_mfma(
    const float* __restrict__ A,
    const float* __restrict__ noise,
    const float* __restrict__ br,
    const float* __restrict__ bn,
    const short* __restrict__ Bh,
    const short* __restrict__ Bl,
    float* __restrict__ out)
{
    // fp32 A ring: RING_D slots x [64 rows][32 floats] row-major linear.
    __shared__ __align__(16) float ringA[RING_D * M_TILE * 32];
    __shared__ float Cs[M_TILE * CS_LD];
    __shared__ float s_p1[M_TILE], s_p2[M_TILE];
    __shared__ int   s_e1[M_TILE], s_e2[M_TILE];

    const int tid  = threadIdx.x;
    const int lane = tid & 63;
    const int wid  = tid >> 6;   // wave: route ntile wid, noise ntile wid+4
    const int n16  = lane & 15;
    const int quad = lane >> 4;
    const int m0   = blockIdx.x * M_TILE;

    // ---- DMA addressing: linear both sides (rule 21) ----
    // wave instr j (j = 2*wid, 2*wid+1): lane l stages 16B of
    // row j*8 + (l>>3), cols kc*32 + (l&7)*4 .. +4.  Dest = slot + j*256
    // floats + lane*16B  ->  slot[row][col] row-major [64][32].
    const int rlo = lane >> 3;                 // 0..7
    const int c4  = (lane & 7) * 4;            // float col within row
    const int j0  = 2 * wid;
    const float* srcA0 = A + (size_t)(m0 + j0 * 8 + rlo) * D_MODEL + c4;
    const float* srcA1 = A + (size_t)(m0 + j0 * 8 + 8 + rlo) * D_MODEL + c4;

    const short* pBhR = Bh + ((size_t)(wid * 128 + quad) * 16 + n16) * 8;
    const short* pBlR = Bl + ((size_t)(wid * 128 + quad) * 16 + n16) * 8;
    const short* pBhN = Bh + ((size_t)((4 + wid) * 128 + quad) * 16 + n16) * 8;
    const short* pBlN = Bl + ((size_t)((4 + wid) * 128 + quad) * 16 + n16) * 8;

#define DMA_CHUNK(KC_) do {                                                   \
        const int b_ = (KC_) & (RING_D - 1);                                  \
        __builtin_amdgcn_global_load_lds(                                     \
            (gu32*)(srcA0 + (KC_) * 32),                                      \
            (lu32*)(ringA + b_ * (M_TILE * 32) + j0 * 256), 16, 0, 0);        \
        __builtin_amdgcn_global_load_lds(                                     \
            (gu32*)(srcA1 + (KC_) * 32),                                      \
            (lu32*)(ringA + b_ * (M_TILE * 32) + (j0 + 1) * 256), 16, 0, 0);  \
    } while (0)

    floatx4 acc[4][2];   // [m-frag][route/noise]
    #pragma unroll
    for (int i = 0; i < 4; ++i) { acc[i][0] = (floatx4)0.f; acc[i][1] = (floatx4)0.f; }

    // ---- prologue: DMA chunks 0..2 (6 instrs); B(0),B(1) into regs (8) ----
    DMA_CHUNK(0);
    DMA_CHUNK(1);
    DMA_CHUNK(2);
    bf16x8 b0hR = *(const bf16x8*)(pBhR);
    bf16x8 b0lR = *(const bf16x8*)(pBlR);
    bf16x8 b0hN = *(const bf16x8*)(pBhN);
    bf16x8 b0lN = *(const bf16x8*)(pBlN);
    bf16x8 b1hR = *(const bf16x8*)(pBhR + 512);
    bf16x8 b1lR = *(const bf16x8*)(pBlR + 512);
    bf16x8 b1hN = *(const bf16x8*)(pBhN + 512);
    bf16x8 b1lN = *(const bf16x8*)(pBlN + 512);

    #pragma unroll 1
    for (int kc = 0; kc < NCHUNK; ++kc) {
        const int buf = kc & (RING_D - 1);

        // issue B(kc+2) (4 instrs) — pinned before the wait
        bf16x8 b2hR, b2lR, b2hN, b2lN;
        if (kc + 2 < NCHUNK) {
            const int o = (kc + 2) * 512;
            b2hR = *(const bf16x8*)(pBhR + o);
            b2lR = *(const bf16x8*)(pBlR + o);
            b2hN = *(const bf16x8*)(pBhN + o);
            b2lN = *(const bf16x8*)(pBlN + o);
        }
        __builtin_amdgcn_sched_barrier(0);

        // exact counted wait (see header): guarantees A(kc) in LDS and B(kc)
        // in regs, keeps A(kc+2)[,A(kc+3)],B(kc+1),B(kc+2) in flight.
        if (kc == 0)            asm volatile("s_waitcnt vmcnt(8)"  ::: "memory");
        else if (kc == 1)       asm volatile("s_waitcnt vmcnt(10)" ::: "memory");
        else if (kc < NCHUNK-2) asm volatile("s_waitcnt vmcnt(12)" ::: "memory");
        else if (kc == NCHUNK-2)asm volatile("s_waitcnt vmcnt(4)"  ::: "memory");
        else                    asm volatile("s_waitcnt vmcnt(0)"  ::: "memory");
        __builtin_amdgcn_s_barrier();   // all waves' A(kc) now visible
        __builtin_amdgcn_sched_barrier(0);

        // DMA A(kc+3) into slot (kc-1)%4 — safe: every wave's reads of chunk
        // kc-1 retired (lgkm before its MFMAs) before the barrier above.
        if (kc + 3 < NCHUNK) DMA_CHUNK(kc + 3);

        // frag reads from slot kc: row = mf*16+n16, floats quad*8..+8
        float4 fa[4], fb[4];
        #pragma unroll
        for (int mf = 0; mf < 4; ++mf) {
            const float* p = &ringA[buf * (M_TILE * 32) + (mf * 16 + n16) * 32 + quad * 8];
            fa[mf] = *(const float4*)(p);
            fb[mf] = *(const float4*)(p + 4);
        }

        // cvt + 24 MFMAs (8 independent acc chains, depth 3)
        #pragma unroll
        for (int mf = 0; mf < 4; ++mf) {
            bf16x8 ah, al;
            cvt8r(fa[mf], fb[mf], &ah, &al);
            acc[mf][0] = __builtin_amdgcn_mfma_f32_16x16x32_bf16(ah, b0hR, acc[mf][0], 0, 0, 0);
            acc[mf][0] = __builtin_amdgcn_mfma_f32_16x16x32_bf16(ah, b0lR, acc[mf][0], 0, 0, 0);
            acc[mf][0] = __builtin_amdgcn_mfma_f32_16x16x32_bf16(al, b0hR, acc[mf][0], 0, 0, 0);
            acc[mf][1] = __builtin_amdgcn_mfma_f32_16x16x32_bf16(ah, b0hN, acc[mf][1], 0, 0, 0);
            acc[mf][1] = __builtin_amdgcn_mfma_f32_16x16x32_bf16(ah, b0lN, acc[mf][1], 0, 0, 0);
            acc[mf][1] = __builtin_amdgcn_mfma_f32_16x16x32_bf16(al, b0hN, acc[mf][1], 0, 0, 0);
        }

        // rotate B registers (named 3-stage, no dynamic indexing)
        b0hR = b1hR; b0lR = b1lR; b0hN = b1hN; b0lN = b1lN;
        b1hR = b2hR; b1lR = b2lR; b1hN = b2hN; b1lN = b2lN;
    }
#undef DMA_CHUNK

    // ---- lane-local fuse: noisy = route + noise * softplus(noise_logit) ----
    // D layout: col = lane&15 (expert within ntile), row = quad*4 + rr
    {
        int e = wid * 16 + n16;
        float brv = br[e], bnv = bn[e];
        #pragma unroll
        for (int mf = 0; mf < 4; ++mf)
            #pragma unroll
            for (int rr = 0; rr < 4; ++rr) {
                int t = mf * 16 + quad * 4 + rr;
                float nz    = noise[(size_t)(m0 + t) * NE + e];
                float route = acc[mf][0][rr] + brv;
                float nl    = acc[mf][1][rr] + bnv;
                Cs[t * CS_LD + e] = fmaf(nz, softplus_f(nl), route);
            }
    }
    __syncthreads();

    // ---- top-2 + softmax (one thread per token; in-order scan = stable ties) ----
    if (tid < M_TILE) {
        const int t = tid;
        float v1 = -INFINITY, v2 = -INFINITY;
        int e1 = 0, e2 = 0;
        #pragma unroll
        for (int e4 = 0; e4 < 16; ++e4) {
            float4 q = *(const float4*)&Cs[t * CS_LD + e4 * 4];
            float qa[4] = {q.x, q.y, q.z, q.w};
            #pragma unroll
            for (int c = 0; c < 4; ++c) {
                float v = qa[c];
                int e = e4 * 4 + c;
                if (v > v1) { v2 = v1; e2 = e1; v1 = v; e1 = e; }
                else if (v > v2) { v2 = v; e2 = e; }
            }
        }
        float ex = expf(v2 - v1);
        float denom = 1.f + ex;
        s_p1[t] = 1.f / denom;
        s_p2[t] = ex / denom;
        s_e1[t] = e1;
        s_e2[t] = e2;
        float2 iv = make_float2((float)e1, (float)e2);
        *(float2*)(out + OUT_IDX_BASE + (size_t)(m0 + t) * 2) = iv;
    }
    __syncthreads();

    // ---- coalesced scatter of router_output [64 tokens x 64 experts] ----
    #pragma unroll
    for (int i = 0; i < 4; ++i) {
        int gi = i * 256 + tid;       // 0..1023 float4s
        int t  = gi >> 4;
        int e0 = (gi & 15) * 4;
        float p1 = s_p1[t], p2 = s_p2[t];
        int   e1 = s_e1[t], e2 = s_e2[t];
        float4 v;
        v.x = (e0 + 0 == e1) ? p1 : ((e0 + 0 == e2) ? p2 : 0.f);
        v.y = (e0 + 1 == e1) ? p1 : ((e0 + 1 == e2) ? p2 : 0.f);
        v.z = (e0 + 2 == e1) ? p1 : ((e0 + 2 == e2) ? p2 : 0.f);
        v.w = (e0 + 3 == e1) ? p1 : ((e0 + 3 == e2) ? p2 : 0.f);
        *(float4*)(out + (size_t)(m0 + t) * NE + e0) = v;
    }
}

extern "C" void kernel_launch(void* const* d_in, const int* in_sizes, int n_in,
                              void* d_out, int out_size, void* d_ws, size_t ws_size,
                              hipStream_t stream) {
    const float* A     = (const float*)d_in[0];
    const float* noise = (const float*)d_in[1];
    const float* Wr    = (const float*)d_in[2];
    const float* br    = (const float*)d_in[3];
    const float* Wn    = (const float*)d_in[4];
    const float* bn    = (const float*)d_in[5];
    float* out = (float*)d_out;

    short* Bh = (short*)d_ws;
    short* Bl = Bh + W_ELEMS;

    prepack_w<<<dim3(W_ELEMS / 8 / 256), dim3(256), 0, stream>>>(Wr, Wn, Bh, Bl);
    router_mfma<<<dim3(T_TOKENS / M_TILE), dim3(256), 0, stream>>>(A, noise, br, bn, Bh, Bl, out);
}

// Round 5
// 230.100 us; speedup vs baseline: 1.1355x; 1.0184x over previous
//
#include <hip/hip_runtime.h>
#include <hip/hip_bf16.h>
#include <math.h>

// NoisyTopkRouter round 11: r6 (proven 80.2us best) + modeled local wins.
// Post-mortems r7-r10: occupancy x2, barrier-free, DMA-ring, exact-counted
// pipeline -> all neutral/worse; latency/MLP theory falsified (r10 had
// ~14KB/wave verified in flight, no change). r6's structure is the local
// optimum; this round keeps it verbatim and adds only:
//  1. KSTAGE 64 (16 barriers, was 32): halves the pre-barrier vmcnt(0)
//     drain events of the raw-A prefetch (~400-1500cyc each).
//  2. Noise reg-prefetch at stage 13: epilogue's 16 cold HBM scalar
//     loads/thread issued ~6K cycles before use instead of serially after
//     the last barrier.
//  3. Top-2 scan parallel across all 4 waves (16 tokens each; 2-way bank
//     aliasing = free) instead of wave-0-only.
//  4. B: chunk0 prefetched 1 stage ahead in regs, chunk1 issued at top of
//     its stage. No sched_barrier fences, no unroll-1 (m141 lesson).
// Numerics identical: bf16 hi/lo split, 3-term MFMA, same epilogue math.

#define T_TOKENS 32768
#define D_MODEL  1024
#define NE       64
#define NCOL     128
#define M_TILE   64
#define KSTAGE   64
#define NSTAGE   16
#define CS_LD    68
#define OUT_IDX_BASE ((size_t)T_TOKENS * NE)
#define W_ELEMS  (NCOL * D_MODEL)

typedef short  bf16x8  __attribute__((ext_vector_type(8)));
typedef float  floatx4 __attribute__((ext_vector_type(4)));

__device__ __forceinline__ float softplus_f(float x) {
    return fmaxf(x, 0.f) + log1pf(expf(-fabsf(x)));
}

// 8 floats -> packed bf16 hi (int4) + bf16 lo (int4). RNE hi, exact residual,
// RNE lo — numerically identical to rounds 2-10.
__device__ __forceinline__ void cvt8(const float4 a, const float4 b,
                                     int4* hi, int4* lo) {
    float v[8] = {a.x, a.y, a.z, a.w, b.x, b.y, b.z, b.w};
    int hw[4], lw[4];
    #pragma unroll
    for (int p = 0; p < 4; ++p) {
        float2 f2 = make_float2(v[2 * p], v[2 * p + 1]);
        __hip_bfloat162 h2 = __float22bfloat162_rn(f2);
        int u; __builtin_memcpy(&u, &h2, 4);
        float h0 = __uint_as_float(((unsigned)u) << 16);
        float h1 = __uint_as_float(((unsigned)u) & 0xFFFF0000u);
        float2 l2 = make_float2(v[2 * p] - h0, v[2 * p + 1] - h1);
        __hip_bfloat162 L2 = __float22bfloat162_rn(l2);
        int ul; __builtin_memcpy(&ul, &L2, 4);
        hw[p] = u; lw[p] = ul;
    }
    *hi = make_int4(hw[0], hw[1], hw[2], hw[3]);
    *lo = make_int4(lw[0], lw[1], lw[2], lw[3]);
}

// ---------------- prepack: W -> hi/lo bf16 in B-frag order ----------------
// elem index = ((ntile*128 + kgrp)*16 + n16)*8 + j ; value = W[ntile*16+n16][kgrp*8+j]
__global__ __launch_bounds__(256) void prepack_w(
    const float* __restrict__ Wr, const float* __restrict__ Wn,
    short* __restrict__ Bh, short* __restrict__ Bl)
{
    int g   = blockIdx.x * 256 + threadIdx.x;
    int n   = g & 15;
    int kg  = (g >> 4) & 127;
    int t2  = g >> 11;
    int col = t2 * 16 + n;
    const float* src = (col < NE ? Wr + (size_t)col * D_MODEL
                                 : Wn + (size_t)(col - NE) * D_MODEL) + kg * 8;
    float4 a = *(const float4*)src;
    float4 b = *(const float4*)(src + 4);
    int4 hi, lo;
    cvt8(a, b, &hi, &lo);
    *(int4*)(Bh + (size_t)g * 8) = hi;
    *(int4*)(Bl + (size_t)g * 8) = lo;
}

// ---------------- main fused kernel ----------------
__global__ __launch_bounds__(256, 2) void router_mfma(
    const float* __restrict__ A,
    const float* __restrict__ noise,
    const float* __restrict__ br,
    const float* __restrict__ bn,
    const short* __restrict__ Bh,
    const short* __restrict__ Bl,
    float* __restrict__ out)
{
    // frag-order staged A, K=64 per stage (2 MFMA chunks), double-buffered.
    __shared__ __align__(16) short Ah[2][M_TILE * KSTAGE];
    __shared__ __align__(16) short Al[2][M_TILE * KSTAGE];
    __shared__ float Cs[M_TILE * CS_LD];
    __shared__ float s_p1[M_TILE], s_p2[M_TILE];
    __shared__ int   s_e1[M_TILE], s_e2[M_TILE];

    const int tid  = threadIdx.x;
    const int lane = tid & 63;
    const int wid  = tid >> 6;   // wave: route ntile wid, noise ntile wid+4
    const int n16  = lane & 15;
    const int quad = lane >> 4;
    const int m0   = blockIdx.x * M_TILE;

    // staging: row r = tid&63, kgrp g = tid>>6. Thread stages k-floats
    // [s*64 + g*8 .. +8) (chunk0, kgrp g) and [s*64 + 32 + g*8 ..) (chunk1).
    // frag-order elem = ((c*4 + kg)*64 + row)*8 -> 16B aligned, conflict-free
    // (same pattern as r6, which measured SQ_LDS_BANK_CONFLICT == 0).
    const int r  = tid & 63;
    const int g  = tid >> 6;
    const float* pA = A + (size_t)(m0 + r) * D_MODEL + g * 8;
    const int sBase = (g * M_TILE + r) * 8;            // chunk0 dest
    // chunk1 dest = sBase + 4*64*8 = sBase + 2048

    const short* pBhR = Bh + ((size_t)(wid * 128 + quad) * 16 + n16) * 8;
    const short* pBlR = Bl + ((size_t)(wid * 128 + quad) * 16 + n16) * 8;
    const short* pBhN = Bh + ((size_t)((4 + wid) * 128 + quad) * 16 + n16) * 8;
    const short* pBlN = Bl + ((size_t)((4 + wid) * 128 + quad) * 16 + n16) * 8;

    floatx4 acc[4][2];   // [m-frag][route/noise]
    #pragma unroll
    for (int i = 0; i < 4; ++i) { acc[i][0] = (floatx4)0.f; acc[i][1] = (floatx4)0.f; }

    // ---- prologue: stage 0 into buf 0; raw A for stage 1; B chunk0(0) ----
    {
        float4 a0 = *(const float4*)(pA);
        float4 a1 = *(const float4*)(pA + 4);
        float4 a2 = *(const float4*)(pA + 32);
        float4 a3 = *(const float4*)(pA + 36);
        int4 hi, lo;
        cvt8(a0, a1, &hi, &lo);
        *(int4*)&Ah[0][sBase] = hi;
        *(int4*)&Al[0][sBase] = lo;
        cvt8(a2, a3, &hi, &lo);
        *(int4*)&Ah[0][sBase + 2048] = hi;
        *(int4*)&Al[0][sBase + 2048] = lo;
    }
    float4 nx0a = *(const float4*)(pA + KSTAGE);
    float4 nx0b = *(const float4*)(pA + KSTAGE + 4);
    float4 nx1a = *(const float4*)(pA + KSTAGE + 32);
    float4 nx1b = *(const float4*)(pA + KSTAGE + 36);
    bf16x8 c0hR = *(const bf16x8*)(pBhR);
    bf16x8 c0lR = *(const bf16x8*)(pBlR);
    bf16x8 c0hN = *(const bf16x8*)(pBhN);
    bf16x8 c0lN = *(const bf16x8*)(pBlN);
    __syncthreads();

    float nz[4][4];   // noise prefetch (filled at stage NSTAGE-3)

    #pragma unroll 2
    for (int s = 0; s < NSTAGE; ++s) {
        const int cur = s & 1, nxt = cur ^ 1;

        // raw A for stage s+2 (issued earliest -> max distance to the
        // pre-barrier drain at the bottom of this iteration)
        float4 f0a, f0b, f1a, f1b;
        if (s + 2 < NSTAGE) {
            const float* q = pA + (s + 2) * KSTAGE;
            f0a = *(const float4*)(q);
            f0b = *(const float4*)(q + 4);
            f1a = *(const float4*)(q + 32);
            f1b = *(const float4*)(q + 36);
        }

        // B chunk1 of this stage (used ~400+ cyc later, L2-hit covered)
        const int ob1 = (s * 2 + 1) * 512;
        bf16x8 c1hR = *(const bf16x8*)(pBhR + ob1);
        bf16x8 c1lR = *(const bf16x8*)(pBlR + ob1);
        bf16x8 c1hN = *(const bf16x8*)(pBhN + ob1);
        bf16x8 c1lN = *(const bf16x8*)(pBlN + ob1);
        // B chunk0 of next stage
        bf16x8 n0hR, n0lR, n0hN, n0lN;
        if (s + 1 < NSTAGE) {
            const int ob0 = (s + 1) * 2 * 512;
            n0hR = *(const bf16x8*)(pBhR + ob0);
            n0lR = *(const bf16x8*)(pBlR + ob0);
            n0hN = *(const bf16x8*)(pBhN + ob0);
            n0lN = *(const bf16x8*)(pBlN + ob0);
        }

        // noise prefetch: 16 scalar loads, ~3 stages before use
        if (s == NSTAGE - 3) {
            const int e = wid * 16 + n16;
            #pragma unroll
            for (int mf = 0; mf < 4; ++mf)
                #pragma unroll
                for (int rr = 0; rr < 4; ++rr)
                    nz[mf][rr] = noise[(size_t)(m0 + mf * 16 + quad * 4 + rr) * NE + e];
        }

        // ---- chunk 0: frags + 24 MFMAs ----
        #pragma unroll
        for (int mf = 0; mf < 4; ++mf) {
            const int gi = (quad * M_TILE + mf * 16 + n16) * 8;
            bf16x8 afh = *(const bf16x8*)&Ah[cur][gi];
            bf16x8 afl = *(const bf16x8*)&Al[cur][gi];
            acc[mf][0] = __builtin_amdgcn_mfma_f32_16x16x32_bf16(afh, c0hR, acc[mf][0], 0, 0, 0);
            acc[mf][0] = __builtin_amdgcn_mfma_f32_16x16x32_bf16(afh, c0lR, acc[mf][0], 0, 0, 0);
            acc[mf][0] = __builtin_amdgcn_mfma_f32_16x16x32_bf16(afl, c0hR, acc[mf][0], 0, 0, 0);
            acc[mf][1] = __builtin_amdgcn_mfma_f32_16x16x32_bf16(afh, c0hN, acc[mf][1], 0, 0, 0);
            acc[mf][1] = __builtin_amdgcn_mfma_f32_16x16x32_bf16(afh, c0lN, acc[mf][1], 0, 0, 0);
            acc[mf][1] = __builtin_amdgcn_mfma_f32_16x16x32_bf16(afl, c0hN, acc[mf][1], 0, 0, 0);
        }
        // ---- chunk 1: frags + 24 MFMAs ----
        #pragma unroll
        for (int mf = 0; mf < 4; ++mf) {
            const int gi = ((4 + quad) * M_TILE + mf * 16 + n16) * 8;
            bf16x8 afh = *(const bf16x8*)&Ah[cur][gi];
            bf16x8 afl = *(const bf16x8*)&Al[cur][gi];
            acc[mf][0] = __builtin_amdgcn_mfma_f32_16x16x32_bf16(afh, c1hR, acc[mf][0], 0, 0, 0);
            acc[mf][0] = __builtin_amdgcn_mfma_f32_16x16x32_bf16(afh, c1lR, acc[mf][0], 0, 0, 0);
            acc[mf][0] = __builtin_amdgcn_mfma_f32_16x16x32_bf16(afl, c1hR, acc[mf][0], 0, 0, 0);
            acc[mf][1] = __builtin_amdgcn_mfma_f32_16x16x32_bf16(afh, c1hN, acc[mf][1], 0, 0, 0);
            acc[mf][1] = __builtin_amdgcn_mfma_f32_16x16x32_bf16(afh, c1lN, acc[mf][1], 0, 0, 0);
            acc[mf][1] = __builtin_amdgcn_mfma_f32_16x16x32_bf16(afl, c1hN, acc[mf][1], 0, 0, 0);
        }

        // stage s+1 (raw regs loaded last iteration)
        if (s + 1 < NSTAGE) {
            int4 hi, lo;
            cvt8(nx0a, nx0b, &hi, &lo);
            *(int4*)&Ah[nxt][sBase] = hi;
            *(int4*)&Al[nxt][sBase] = lo;
            cvt8(nx1a, nx1b, &hi, &lo);
            *(int4*)&Ah[nxt][sBase + 2048] = hi;
            *(int4*)&Al[nxt][sBase + 2048] = lo;
        }

        __syncthreads();

        nx0a = f0a; nx0b = f0b; nx1a = f1a; nx1b = f1b;
        c0hR = n0hR; c0lR = n0lR; c0hN = n0hN; c0lN = n0lN;
    }

    // ---- lane-local fuse: noisy = route + noise * softplus(noise_logit) ----
    // D layout: col = lane&15 (expert within ntile), row = quad*4 + rr
    {
        const int e = wid * 16 + n16;
        float brv = br[e], bnv = bn[e];
        #pragma unroll
        for (int mf = 0; mf < 4; ++mf)
            #pragma unroll
            for (int rr = 0; rr < 4; ++rr) {
                int t = mf * 16 + quad * 4 + rr;
                float route = acc[mf][0][rr] + brv;
                float nl    = acc[mf][1][rr] + bnv;
                Cs[t * CS_LD + e] = fmaf(nz[mf][rr], softplus_f(nl), route);
            }
    }
    __syncthreads();

    // ---- top-2 + softmax: 4 waves x 16 tokens (in-order scan = stable ties)
    // bank check: word = t*68 mod 32 = (lane&15)*4 -> 2-way aliasing = free.
    if (lane < 16) {
        const int t = wid * 16 + lane;
        float v1 = -INFINITY, v2 = -INFINITY;
        int e1 = 0, e2 = 0;
        #pragma unroll
        for (int e4 = 0; e4 < 16; ++e4) {
            float4 q = *(const float4*)&Cs[t * CS_LD + e4 * 4];
            float qa[4] = {q.x, q.y, q.z, q.w};
            #pragma unroll
            for (int c = 0; c < 4; ++c) {
                float v = qa[c];
                int e = e4 * 4 + c;
                if (v > v1) { v2 = v1; e2 = e1; v1 = v; e1 = e; }
                else if (v > v2) { v2 = v; e2 = e; }
            }
        }
        float ex = expf(v2 - v1);
        float denom = 1.f + ex;
        s_p1[t] = 1.f / denom;
        s_p2[t] = ex / denom;
        s_e1[t] = e1;
        s_e2[t] = e2;
        float2 iv = make_float2((float)e1, (float)e2);
        *(float2*)(out + OUT_IDX_BASE + (size_t)(m0 + t) * 2) = iv;
    }
    __syncthreads();

    // ---- coalesced scatter of router_output [64 tokens x 64 experts] ----
    #pragma unroll
    for (int i = 0; i < 4; ++i) {
        int gi = i * 256 + tid;       // 0..1023 float4s
        int t  = gi >> 4;
        int e0 = (gi & 15) * 4;
        float p1 = s_p1[t], p2 = s_p2[t];
        int   e1 = s_e1[t], e2 = s_e2[t];
        float4 v;
        v.x = (e0 + 0 == e1) ? p1 : ((e0 + 0 == e2) ? p2 : 0.f);
        v.y = (e0 + 1 == e1) ? p1 : ((e0 + 1 == e2) ? p2 : 0.f);
        v.z = (e0 + 2 == e1) ? p1 : ((e0 + 2 == e2) ? p2 : 0.f);
        v.w = (e0 + 3 == e1) ? p1 : ((e0 + 3 == e2) ? p2 : 0.f);
        *(float4*)(out + (size_t)(m0 + t) * NE + e0) = v;
    }
}

extern "C" void kernel_launch(void* const* d_in, const int* in_sizes, int n_in,
                              void* d_out, int out_size, void* d_ws, size_t ws_size,
                              hipStream_t stream) {
    const float* A     = (const float*)d_in[0];
    const float* noise = (const float*)d_in[1];
    const float* Wr    = (const float*)d_in[2];
    const float* br    = (const float*)d_in[3];
    const float* Wn    = (const float*)d_in[4];
    const float* bn    = (const float*)d_in[5];
    float* out = (float*)d_out;

    short* Bh = (short*)d_ws;
    short* Bl = Bh + W_ELEMS;

    prepack_w<<<dim3(W_ELEMS / 8 / 256), dim3(256), 0, stream>>>(Wr, Wn, Bh, Bl);
    router_mfma<<<dim3(T_TOKENS / M_TILE), dim3(256), 0, stream>>>(A, noise, br, bn, Bh, Bl, out);
}

// Round 6
// 222.310 us; speedup vs baseline: 1.1753x; 1.0350x over previous
//
#include <hip/hip_runtime.h>
#include <hip/hip_bf16.h>
#include <math.h>

// NoisyTopkRouter round 12: r11 + per-block K-phase rotation.
// Unified observation r6-r11: dur ~= FETCH_SIZE / ~1.0 TB/s in EVERY round
// (80us/71.8MB, 85/73.9, 89/71.8, 86/71.8, 81/71.8) while occupancy x2,
// barrier removal, and verified 14KB/wave in-flight depth all changed
// nothing -> the cap is the memory system's SERVICE rate for this address
// stream, not our request rate.
// Theory: K-lockstep channel camping. All 512 blocks march K in phase; at
// stage s every block reads A bytes row*4096 + s*256 + {0,128} -> the same
// two 128B line positions within every 4KB row, chip-wide -> only a 1/16
// slice of HBM channel positions active at any instant (if channel
// interleave uses addr bits in the 256B-2KB range). Structural ~6-16x BW
// derate invisible to occupancy/pipelining -- matches all six rounds.
// Fix (ONLY change vs r11): block b processes K-windows in rotated order
// (s + b) mod 16 -> at any instant blocks collectively cover all 16 256B
// positions -> all channels busy. B chunk indices rotate identically.
// Numerics: fp32 accumulation reassociation only (~1e-6, << the 1e-3
// bf16-split error that has passed since round 2).

#define T_TOKENS 32768
#define D_MODEL  1024
#define NE       64
#define NCOL     128
#define M_TILE   64
#define KSTAGE   64
#define NSTAGE   16
#define CS_LD    68
#define OUT_IDX_BASE ((size_t)T_TOKENS * NE)
#define W_ELEMS  (NCOL * D_MODEL)

typedef short  bf16x8  __attribute__((ext_vector_type(8)));
typedef float  floatx4 __attribute__((ext_vector_type(4)));

__device__ __forceinline__ float softplus_f(float x) {
    return fmaxf(x, 0.f) + log1pf(expf(-fabsf(x)));
}

// 8 floats -> packed bf16 hi (int4) + bf16 lo (int4). RNE hi, exact residual,
// RNE lo — numerically identical to rounds 2-11.
__device__ __forceinline__ void cvt8(const float4 a, const float4 b,
                                     int4* hi, int4* lo) {
    float v[8] = {a.x, a.y, a.z, a.w, b.x, b.y, b.z, b.w};
    int hw[4], lw[4];
    #pragma unroll
    for (int p = 0; p < 4; ++p) {
        float2 f2 = make_float2(v[2 * p], v[2 * p + 1]);
        __hip_bfloat162 h2 = __float22bfloat162_rn(f2);
        int u; __builtin_memcpy(&u, &h2, 4);
        float h0 = __uint_as_float(((unsigned)u) << 16);
        float h1 = __uint_as_float(((unsigned)u) & 0xFFFF0000u);
        float2 l2 = make_float2(v[2 * p] - h0, v[2 * p + 1] - h1);
        __hip_bfloat162 L2 = __float22bfloat162_rn(l2);
        int ul; __builtin_memcpy(&ul, &L2, 4);
        hw[p] = u; lw[p] = ul;
    }
    *hi = make_int4(hw[0], hw[1], hw[2], hw[3]);
    *lo = make_int4(lw[0], lw[1], lw[2], lw[3]);
}

// ---------------- prepack: W -> hi/lo bf16 in B-frag order ----------------
// elem index = ((ntile*128 + kgrp)*16 + n16)*8 + j ; value = W[ntile*16+n16][kgrp*8+j]
__global__ __launch_bounds__(256) void prepack_w(
    const float* __restrict__ Wr, const float* __restrict__ Wn,
    short* __restrict__ Bh, short* __restrict__ Bl)
{
    int g   = blockIdx.x * 256 + threadIdx.x;
    int n   = g & 15;
    int kg  = (g >> 4) & 127;
    int t2  = g >> 11;
    int col = t2 * 16 + n;
    const float* src = (col < NE ? Wr + (size_t)col * D_MODEL
                                 : Wn + (size_t)(col - NE) * D_MODEL) + kg * 8;
    float4 a = *(const float4*)src;
    float4 b = *(const float4*)(src + 4);
    int4 hi, lo;
    cvt8(a, b, &hi, &lo);
    *(int4*)(Bh + (size_t)g * 8) = hi;
    *(int4*)(Bl + (size_t)g * 8) = lo;
}

// ---------------- main fused kernel ----------------
__global__ __launch_bounds__(256, 2) void router_mfma(
    const float* __restrict__ A,
    const float* __restrict__ noise,
    const float* __restrict__ br,
    const float* __restrict__ bn,
    const short* __restrict__ Bh,
    const short* __restrict__ Bl,
    float* __restrict__ out)
{
    // frag-order staged A, K=64 per stage (2 MFMA chunks), double-buffered.
    __shared__ __align__(16) short Ah[2][M_TILE * KSTAGE];
    __shared__ __align__(16) short Al[2][M_TILE * KSTAGE];
    __shared__ float Cs[M_TILE * CS_LD];
    __shared__ float s_p1[M_TILE], s_p2[M_TILE];
    __shared__ int   s_e1[M_TILE], s_e2[M_TILE];

    const int tid  = threadIdx.x;
    const int lane = tid & 63;
    const int wid  = tid >> 6;   // wave: route ntile wid, noise ntile wid+4
    const int n16  = lane & 15;
    const int quad = lane >> 4;
    const int m0   = blockIdx.x * M_TILE;

    // per-block K-phase: block processes windows (s + phase) mod 16
    const int phase = blockIdx.x & 15;

    // staging: row r = tid&63, kgrp g = tid>>6 (same proven conflict-free
    // pattern as r6/r11; SQ_LDS_BANK_CONFLICT == 0).
    const int r  = tid & 63;
    const int g  = tid >> 6;
    const float* pA = A + (size_t)(m0 + r) * D_MODEL + g * 8;
    const int sBase = (g * M_TILE + r) * 8;            // chunk0 dest
    // chunk1 dest = sBase + 2048

    const short* pBhR = Bh + ((size_t)(wid * 128 + quad) * 16 + n16) * 8;
    const short* pBlR = Bl + ((size_t)(wid * 128 + quad) * 16 + n16) * 8;
    const short* pBhN = Bh + ((size_t)((4 + wid) * 128 + quad) * 16 + n16) * 8;
    const short* pBlN = Bl + ((size_t)((4 + wid) * 128 + quad) * 16 + n16) * 8;

    floatx4 acc[4][2];   // [m-frag][route/noise]
    #pragma unroll
    for (int i = 0; i < 4; ++i) { acc[i][0] = (floatx4)0.f; acc[i][1] = (floatx4)0.f; }

    // ---- prologue: stage window w0 into buf 0; raw A for w1; B chunk0(w0) ----
    const int w0 = phase;
    const int w1 = (phase + 1) & 15;
    {
        const float* q = pA + w0 * KSTAGE;
        float4 a0 = *(const float4*)(q);
        float4 a1 = *(const float4*)(q + 4);
        float4 a2 = *(const float4*)(q + 32);
        float4 a3 = *(const float4*)(q + 36);
        int4 hi, lo;
        cvt8(a0, a1, &hi, &lo);
        *(int4*)&Ah[0][sBase] = hi;
        *(int4*)&Al[0][sBase] = lo;
        cvt8(a2, a3, &hi, &lo);
        *(int4*)&Ah[0][sBase + 2048] = hi;
        *(int4*)&Al[0][sBase + 2048] = lo;
    }
    float4 nx0a = *(const float4*)(pA + w1 * KSTAGE);
    float4 nx0b = *(const float4*)(pA + w1 * KSTAGE + 4);
    float4 nx1a = *(const float4*)(pA + w1 * KSTAGE + 32);
    float4 nx1b = *(const float4*)(pA + w1 * KSTAGE + 36);
    bf16x8 c0hR = *(const bf16x8*)(pBhR + w0 * 1024);
    bf16x8 c0lR = *(const bf16x8*)(pBlR + w0 * 1024);
    bf16x8 c0hN = *(const bf16x8*)(pBhN + w0 * 1024);
    bf16x8 c0lN = *(const bf16x8*)(pBlN + w0 * 1024);
    __syncthreads();

    float nz[4][4];   // noise prefetch (filled at stage NSTAGE-3)

    #pragma unroll 2
    for (int s = 0; s < NSTAGE; ++s) {
        const int cur = s & 1, nxt = cur ^ 1;
        const int ps  = (s + phase) & 15;    // physical K-window this stage

        // raw A for stage s+2 (window (ps+2) mod 16)
        float4 f0a, f0b, f1a, f1b;
        if (s + 2 < NSTAGE) {
            const float* q = pA + ((ps + 2) & 15) * KSTAGE;
            f0a = *(const float4*)(q);
            f0b = *(const float4*)(q + 4);
            f1a = *(const float4*)(q + 32);
            f1b = *(const float4*)(q + 36);
        }

        // B chunk1 of this window (used ~400+ cyc later, L2-hit covered)
        const int ob1 = (ps * 2 + 1) * 512;
        bf16x8 c1hR = *(const bf16x8*)(pBhR + ob1);
        bf16x8 c1lR = *(const bf16x8*)(pBlR + ob1);
        bf16x8 c1hN = *(const bf16x8*)(pBhN + ob1);
        bf16x8 c1lN = *(const bf16x8*)(pBlN + ob1);
        // B chunk0 of next window
        bf16x8 n0hR, n0lR, n0hN, n0lN;
        if (s + 1 < NSTAGE) {
            const int ob0 = ((ps + 1) & 15) * 1024;
            n0hR = *(const bf16x8*)(pBhR + ob0);
            n0lR = *(const bf16x8*)(pBlR + ob0);
            n0hN = *(const bf16x8*)(pBhN + ob0);
            n0lN = *(const bf16x8*)(pBlN + ob0);
        }

        // noise prefetch: 16 scalar loads, ~3 stages before use
        if (s == NSTAGE - 3) {
            const int e = wid * 16 + n16;
            #pragma unroll
            for (int mf = 0; mf < 4; ++mf)
                #pragma unroll
                for (int rr = 0; rr < 4; ++rr)
                    nz[mf][rr] = noise[(size_t)(m0 + mf * 16 + quad * 4 + rr) * NE + e];
        }

        // ---- chunk 0: frags + 24 MFMAs ----
        #pragma unroll
        for (int mf = 0; mf < 4; ++mf) {
            const int gi = (quad * M_TILE + mf * 16 + n16) * 8;
            bf16x8 afh = *(const bf16x8*)&Ah[cur][gi];
            bf16x8 afl = *(const bf16x8*)&Al[cur][gi];
            acc[mf][0] = __builtin_amdgcn_mfma_f32_16x16x32_bf16(afh, c0hR, acc[mf][0], 0, 0, 0);
            acc[mf][0] = __builtin_amdgcn_mfma_f32_16x16x32_bf16(afh, c0lR, acc[mf][0], 0, 0, 0);
            acc[mf][0] = __builtin_amdgcn_mfma_f32_16x16x32_bf16(afl, c0hR, acc[mf][0], 0, 0, 0);
            acc[mf][1] = __builtin_amdgcn_mfma_f32_16x16x32_bf16(afh, c0hN, acc[mf][1], 0, 0, 0);
            acc[mf][1] = __builtin_amdgcn_mfma_f32_16x16x32_bf16(afh, c0lN, acc[mf][1], 0, 0, 0);
            acc[mf][1] = __builtin_amdgcn_mfma_f32_16x16x32_bf16(afl, c0hN, acc[mf][1], 0, 0, 0);
        }
        // ---- chunk 1: frags + 24 MFMAs ----
        #pragma unroll
        for (int mf = 0; mf < 4; ++mf) {
            const int gi = ((4 + quad) * M_TILE + mf * 16 + n16) * 8;
            bf16x8 afh = *(const bf16x8*)&Ah[cur][gi];
            bf16x8 afl = *(const bf16x8*)&Al[cur][gi];
            acc[mf][0] = __builtin_amdgcn_mfma_f32_16x16x32_bf16(afh, c1hR, acc[mf][0], 0, 0, 0);
            acc[mf][0] = __builtin_amdgcn_mfma_f32_16x16x32_bf16(afh, c1lR, acc[mf][0], 0, 0, 0);
            acc[mf][0] = __builtin_amdgcn_mfma_f32_16x16x32_bf16(afl, c1hR, acc[mf][0], 0, 0, 0);
            acc[mf][1] = __builtin_amdgcn_mfma_f32_16x16x32_bf16(afh, c1hN, acc[mf][1], 0, 0, 0);
            acc[mf][1] = __builtin_amdgcn_mfma_f32_16x16x32_bf16(afh, c1lN, acc[mf][1], 0, 0, 0);
            acc[mf][1] = __builtin_amdgcn_mfma_f32_16x16x32_bf16(afl, c1hN, acc[mf][1], 0, 0, 0);
        }

        // stage s+1 (raw regs loaded last iteration)
        if (s + 1 < NSTAGE) {
            int4 hi, lo;
            cvt8(nx0a, nx0b, &hi, &lo);
            *(int4*)&Ah[nxt][sBase] = hi;
            *(int4*)&Al[nxt][sBase] = lo;
            cvt8(nx1a, nx1b, &hi, &lo);
            *(int4*)&Ah[nxt][sBase + 2048] = hi;
            *(int4*)&Al[nxt][sBase + 2048] = lo;
        }

        __syncthreads();

        nx0a = f0a; nx0b = f0b; nx1a = f1a; nx1b = f1b;
        c0hR = n0hR; c0lR = n0lR; c0hN = n0hN; c0lN = n0lN;
    }

    // ---- lane-local fuse: noisy = route + noise * softplus(noise_logit) ----
    // D layout: col = lane&15 (expert within ntile), row = quad*4 + rr
    {
        const int e = wid * 16 + n16;
        float brv = br[e], bnv = bn[e];
        #pragma unroll
        for (int mf = 0; mf < 4; ++mf)
            #pragma unroll
            for (int rr = 0; rr < 4; ++rr) {
                int t = mf * 16 + quad * 4 + rr;
                float route = acc[mf][0][rr] + brv;
                float nl    = acc[mf][1][rr] + bnv;
                Cs[t * CS_LD + e] = fmaf(nz[mf][rr], softplus_f(nl), route);
            }
    }
    __syncthreads();

    // ---- top-2 + softmax: 4 waves x 16 tokens (in-order scan = stable ties)
    if (lane < 16) {
        const int t = wid * 16 + lane;
        float v1 = -INFINITY, v2 = -INFINITY;
        int e1 = 0, e2 = 0;
        #pragma unroll
        for (int e4 = 0; e4 < 16; ++e4) {
            float4 q = *(const float4*)&Cs[t * CS_LD + e4 * 4];
            float qa[4] = {q.x, q.y, q.z, q.w};
            #pragma unroll
            for (int c = 0; c < 4; ++c) {
                float v = qa[c];
                int e = e4 * 4 + c;
                if (v > v1) { v2 = v1; e2 = e1; v1 = v; e1 = e; }
                else if (v > v2) { v2 = v; e2 = e; }
            }
        }
        float ex = expf(v2 - v1);
        float denom = 1.f + ex;
        s_p1[t] = 1.f / denom;
        s_p2[t] = ex / denom;
        s_e1[t] = e1;
        s_e2[t] = e2;
        float2 iv = make_float2((float)e1, (float)e2);
        *(float2*)(out + OUT_IDX_BASE + (size_t)(m0 + t) * 2) = iv;
    }
    __syncthreads();

    // ---- coalesced scatter of router_output [64 tokens x 64 experts] ----
    #pragma unroll
    for (int i = 0; i < 4; ++i) {
        int gi = i * 256 + tid;       // 0..1023 float4s
        int t  = gi >> 4;
        int e0 = (gi & 15) * 4;
        float p1 = s_p1[t], p2 = s_p2[t];
        int   e1 = s_e1[t], e2 = s_e2[t];
        float4 v;
        v.x = (e0 + 0 == e1) ? p1 : ((e0 + 0 == e2) ? p2 : 0.f);
        v.y = (e0 + 1 == e1) ? p1 : ((e0 + 1 == e2) ? p2 : 0.f);
        v.z = (e0 + 2 == e1) ? p1 : ((e0 + 2 == e2) ? p2 : 0.f);
        v.w = (e0 + 3 == e1) ? p1 : ((e0 + 3 == e2) ? p2 : 0.f);
        *(float4*)(out + (size_t)(m0 + t) * NE + e0) = v;
    }
}

extern "C" void kernel_launch(void* const* d_in, const int* in_sizes, int n_in,
                              void* d_out, int out_size, void* d_ws, size_t ws_size,
                              hipStream_t stream) {
    const float* A     = (const float*)d_in[0];
    const float* noise = (const float*)d_in[1];
    const float* Wr    = (const float*)d_in[2];
    const float* br    = (const float*)d_in[3];
    const float* Wn    = (const float*)d_in[4];
    const float* bn    = (const float*)d_in[5];
    float* out = (float*)d_out;

    short* Bh = (short*)d_ws;
    short* Bl = Bh + W_ELEMS;

    prepack_w<<<dim3(W_ELEMS / 8 / 256), dim3(256), 0, stream>>>(Wr, Wn, Bh, Bl);
    router_mfma<<<dim3(T_TOKENS / M_TILE), dim3(256), 0, stream>>>(A, noise, br, bn, Bh, Bl, out);
}